// Round 10
// baseline (1034.018 us; speedup 1.0000x reference)
//
#include <hip/hip_runtime.h>
#include <hip/hip_cooperative_groups.h>
#include <math.h>
#include <stdint.h>

namespace cg = cooperative_groups;

#define NRES 50000
#define NEDGE 1000000
#define PI_F 3.14159265358979323846f
#define NSEG 196   // ceil(NRES/256)

typedef __attribute__((ext_vector_type(8))) short short8;
typedef __attribute__((ext_vector_type(4))) float floatx4;
typedef __attribute__((ext_vector_type(2))) short bf16x2;
typedef __attribute__((address_space(1))) bf16x2* gbf16x2p;

struct f3 { float x, y, z; };
__device__ __forceinline__ f3 ld3(const float* __restrict__ p, int i) {
  return {p[3*i+0], p[3*i+1], p[3*i+2]};
}
__device__ __forceinline__ f3 f3sub(f3 a, f3 b){ return {a.x-b.x, a.y-b.y, a.z-b.z}; }
__device__ __forceinline__ f3 f3cross(f3 a, f3 b){
  return {a.y*b.z - a.z*b.y, a.z*b.x - a.x*b.z, a.x*b.y - a.y*b.x};
}
__device__ __forceinline__ float f3dot(f3 a, f3 b){ return a.x*b.x + a.y*b.y + a.z*b.z; }
__device__ __forceinline__ float swish_fast(float v){
  return v * __builtin_amdgcn_rcpf(1.0f + __expf(-v));
}
__device__ __forceinline__ short f2bf(float f){
  unsigned u = __float_as_uint(f);
  unsigned r = (u + 0x7fffu + ((u >> 16) & 1u)) >> 16;
  return (short)r;
}
__device__ __forceinline__ float bf2f(short s){
  return __uint_as_float(((unsigned)(unsigned short)s) << 16);
}
__device__ __forceinline__ float cos_atan2(float y, float x){
  return x * __builtin_amdgcn_rsqf(fmaxf(x*x + y*y, 1e-30f));
}
__device__ __forceinline__ void atom_pk_bf16(short* addr, bf16x2 v){
  __builtin_amdgcn_global_atomic_fadd_v2bf16((gbf16x2p)(uintptr_t)addr, v);
}
// packed f32x2 -> bf16x2 (RNE) in one instruction
__device__ __forceinline__ unsigned pkbf(float lo, float hi){
  unsigned r;
  asm("v_cvt_pk_bf16_f32 %0, %1, %2" : "=v"(r) : "v"(lo), "v"(hi));
  return r;
}

// ---------------------------------------------------------------------------
// geometry scalars for one edge (shared)
struct EdgeGeo {
  float rb[6];
  float ct, cp, ca1, ca2, ca3;
  float dpe;
};
__device__ __forceinline__ EdgeGeo edge_geo(
    int j, int i,
    const float* __restrict__ pos, const float* __restrict__ posn,
    const float* __restrict__ posc)
{
  EdgeGeo g;
  f3 pj = ld3(pos, j), pi = ld3(pos, i);
  f3 vji = f3sub(pj, pi);
  float nji2 = f3dot(vji, vji);
  float dist = sqrtf(nji2);
  int r0i = (i == 0) ? (NRES - 1) : (i - 1);
  int r1i = (i == NRES - 1) ? 0 : (i + 1);
  f3 vr0 = f3sub(ld3(pos, r0i), pi);
  f3 vr1 = f3sub(ld3(pos, r1i), pi);
  float nr02 = f3dot(vr0, vr0);

  g.ct = f3dot(vji, vr0) * __builtin_amdgcn_rsqf(fmaxf(nji2 * nr02, 1e-30f));
  f3 p1 = f3cross(vr0, vr1);
  f3 p2 = f3cross(vr0, vji);
  float pa = f3dot(p1, p2);
  float pb = f3dot(f3cross(p1, p2), vr0) / (sqrtf(nr02) + 1e-7f);
  g.cp = cos_atan2(pb, pa);

  f3 pni = ld3(posn, i), pci = ld3(posc, i);
  f3 o1x = f3sub(pni, pi);
  f3 o1z = f3cross(o1x, f3cross(o1x, f3sub(pci, pi)));
  float no1z2 = f3dot(o1z, o1z);
  float o1zl = sqrtf(no1z2) + 1e-7f;
  f3 pnj = ld3(posn, j), pcj = ld3(posc, j);
  f3 o2x = f3sub(pnj, pj);
  f3 o2z = f3cross(o2x, f3cross(o2x, f3sub(pcj, pj)));
  float no2z2 = f3dot(o2z, o2z);
  float o2zl = sqrtf(no2z2) + 1e-7f;
  f3 nv = f3cross(o1z, o2z);
  float y1 = f3dot(f3cross(o1x, nv), o1z) / o1zl;
  g.ca1 = cos_atan2(y1, f3dot(o1x, nv));
  g.ca2 = f3dot(o1z, o2z) * __builtin_amdgcn_rsqf(fmaxf(no1z2 * no2z2, 1e-30f));
  float y3 = f3dot(f3cross(nv, o2x), o2z) / o2zl;
  g.ca3 = cos_atan2(y3, f3dot(nv, o2x));

  float u = fminf(dist * (1.0f/11.5f), 1.0f);
  float spu, cpu;
  __sincosf(PI_F * u, &spu, &cpu);
  float fc = 0.5f * (cpu + 1.0f);
  float pref = 0.41702882811414954f * __builtin_amdgcn_rcpf(dist + 1e-6f) * fc;
  {
    float twoc = 2.0f * cpu;
    float s_nm1 = 0.0f, s_n = spu;
    #pragma unroll
    for (int nn = 0; nn < 6; ++nn) {
      g.rb[nn] = pref * s_n;
      float s_np1 = twoc * s_n - s_nm1;
      s_nm1 = s_n; s_n = s_np1;
    }
  }
  g.dpe = (float)(j - i);
  return g;
}

// feature value at position f (0..107), compile-time f
__device__ __forceinline__ float feat_val(const EdgeGeo& g, int f,
                                          const float* ctv, const float* cpv,
                                          const float* cav1, const float* cav2,
                                          const float* cav3)
{
  if (f < 54) {
    int nn = f / 9, l = (f % 9) / 3, m = f % 3;
    return g.rb[nn] * ctv[l] * cpv[m];
  } else {
    int ff = f - 54;
    int t = ff / 18, nn = (ff % 18) / 3, l = ff % 3;
    const float* cav = (t == 0) ? cav1 : (t == 1) ? cav2 : cav3;
    return g.rb[nn] * cav[l];
  }
}

// quarter-split feature pack: 4 threads per edge (quarter q), redundant
// geometry, each writes a disjoint pair-aligned slice. (R6-proven)
__device__ __forceinline__ void edge_features_q(
    int e, int j, int i, int q,
    const float* __restrict__ pos, const float* __restrict__ posn,
    const float* __restrict__ posc, short (*sF)[136])
{
  EdgeGeo g = edge_geo(j, i, pos, posn, posc);
  float ctv[3]  = {1.0f, g.ct,  2.0f*g.ct*g.ct  - 1.0f};
  float cpv[3]  = {1.0f, g.cp,  2.0f*g.cp*g.cp  - 1.0f};
  float cav1[3] = {1.0f, g.ca1, 2.0f*g.ca1*g.ca1 - 1.0f};
  float cav2[3] = {1.0f, g.ca2, 2.0f*g.ca2*g.ca2 - 1.0f};
  float cav3[3] = {1.0f, g.ca3, 2.0f*g.ca3*g.ca3 - 1.0f};

  if (q == 0) {
    #pragma unroll
    for (int f = 0; f < 28; f += 2)
      *(unsigned*)&sF[e][f] = pkbf(feat_val(g, f, ctv, cpv, cav1, cav2, cav3),
                                   feat_val(g, f+1, ctv, cpv, cav1, cav2, cav3));
  } else if (q == 1) {
    #pragma unroll
    for (int f = 28; f < 54; f += 2)
      *(unsigned*)&sF[e][f] = pkbf(feat_val(g, f, ctv, cpv, cav1, cav2, cav3),
                                   feat_val(g, f+1, ctv, cpv, cav1, cav2, cav3));
    const float FRQ[8] = {1.0f, 0.31622776601683794f, 0.1f, 0.03162277660168379f,
                          0.01f, 0.003162277660168379f, 0.001f, 0.0003162277660168379f};
    float cb[8], sb[8];
    #pragma unroll
    for (int p = 0; p < 8; ++p) __sincosf(g.dpe * FRQ[p], &sb[p], &cb[p]);
    #pragma unroll
    for (int p = 0; p < 8; p += 2) {
      *(unsigned*)&sF[e][108 + p] = pkbf(cb[p], cb[p+1]);
      *(unsigned*)&sF[e][116 + p] = pkbf(sb[p], sb[p+1]);
    }
    *(unsigned*)&sF[e][124] = 0u;
    *(unsigned*)&sF[e][126] = 0u;
  } else if (q == 2) {
    #pragma unroll
    for (int f = 54; f < 80; f += 2)
      *(unsigned*)&sF[e][f] = pkbf(feat_val(g, f, ctv, cpv, cav1, cav2, cav3),
                                   feat_val(g, f+1, ctv, cpv, cav1, cav2, cav3));
  } else {
    #pragma unroll
    for (int f = 80; f < 108; f += 2)
      *(unsigned*)&sF[e][f] = pkbf(feat_val(g, f, ctv, cpv, cav1, cav2, cav3),
                                   feat_val(g, f+1, ctv, cpv, cav1, cav2, cav3));
  }
}

// full-row feature pack (used by fallback edge kernel): one thread per edge
__device__ __forceinline__ void edge_features_full(
    int e, int j, int i,
    const float* __restrict__ pos, const float* __restrict__ posn,
    const float* __restrict__ posc, short (*sF)[136])
{
  EdgeGeo g = edge_geo(j, i, pos, posn, posc);
  float ctv[3]  = {1.0f, g.ct,  2.0f*g.ct*g.ct  - 1.0f};
  float cpv[3]  = {1.0f, g.cp,  2.0f*g.cp*g.cp  - 1.0f};
  float cav1[3] = {1.0f, g.ca1, 2.0f*g.ca1*g.ca1 - 1.0f};
  float cav2[3] = {1.0f, g.ca2, 2.0f*g.ca2*g.ca2 - 1.0f};
  float cav3[3] = {1.0f, g.ca3, 2.0f*g.ca3*g.ca3 - 1.0f};
  #pragma unroll
  for (int f = 0; f < 108; f += 2) {
    float v0 = feat_val(g, f,     ctv, cpv, cav1, cav2, cav3);
    float v1 = feat_val(g, f + 1, ctv, cpv, cav1, cav2, cav3);
    *(unsigned*)&sF[e][f] = pkbf(v0, v1);
  }
  const float FRQ[8] = {1.0f, 0.31622776601683794f, 0.1f, 0.03162277660168379f,
                        0.01f, 0.003162277660168379f, 0.001f, 0.0003162277660168379f};
  float cb[8], sb[8];
  #pragma unroll
  for (int q = 0; q < 8; ++q) __sincosf(g.dpe * FRQ[q], &sb[q], &cb[q]);
  #pragma unroll
  for (int q = 0; q < 8; q += 2) {
    *(unsigned*)&sF[e][108 + q] = pkbf(cb[q], cb[q+1]);
    *(unsigned*)&sF[e][116 + q] = pkbf(sb[q], sb[q+1]);
  }
  *(unsigned*)&sF[e][124] = 0u;
  *(unsigned*)&sF[e][126] = 0u;
}

// ---------------------------------------------------------------------------
// device helper: wprep item mapping (shared by coop + standalone)
__device__ __forceinline__ void wprep_item(
    int gid,
    const float* __restrict__ We, const float* __restrict__ Wm,
    const float* __restrict__ Ws, const float* __restrict__ Wu,
    const float* __restrict__ Wo0, const float* __restrict__ Wn0,
    const float* __restrict__ Wo1,
    short* __restrict__ Wef, short* __restrict__ Wmf, short* __restrict__ Wsf,
    short* __restrict__ Wuf, short* __restrict__ Wo0f,
    short* __restrict__ Wn0f, short* __restrict__ Wo1f)
{
  const float* src; short* dst; int NT, K, N, t;
  if      (gid < 16384)  { t = gid;          src = We;  dst = Wef;  NT = 8; K = 124;  N = 128; }
  else if (gid < 32768)  { t = gid - 16384;  src = Wm;  dst = Wmf;  NT = 8; K = 128;  N = 128; }
  else if (gid < 114688) { t = gid - 32768;  src = Ws;  dst = Wsf;  NT = 4; K = 1280; N = 64;  }
  else if (gid < 131072) { t = gid - 114688; src = Wu;  dst = Wuf;  NT = 8; K = 128;  N = 128; }
  else if (gid < 147456) { t = gid - 131072; src = Wo0; dst = Wo0f; NT = 8; K = 128;  N = 128; }
  else if (gid < 151552) { t = gid - 147456; src = Wn0; dst = Wn0f; NT = 2; K = 128;  N = 32;  }
  else                   { t = gid - 151552; src = Wo1; dst = Wo1f; NT = 2; K = 128;  N = 32;  }
  int j = t & 7, lane = (t >> 3) & 63;
  int rest = t >> 9;
  int nt = rest % NT, kt = rest / NT;
  int k = kt*32 + (lane >> 4)*8 + j, n = nt*16 + (lane & 15);
  dst[t] = f2bf((k < K) ? src[k*N + n] : 0.0f);
}

// ---------------------------------------------------------------------------
// COOPERATIVE fused preprocessing: wprep + hist | scan1 | scan2 | scatter.
// 1024 blocks x 256 threads, grid.sync() between phases.
__global__ __launch_bounds__(256) void k_sort_coop(
    const float* __restrict__ We, const float* __restrict__ Wm,
    const float* __restrict__ Ws, const float* __restrict__ Wu,
    const float* __restrict__ Wo0, const float* __restrict__ Wn0,
    const float* __restrict__ Wo1,
    short* __restrict__ Wef, short* __restrict__ Wmf, short* __restrict__ Wsf,
    short* __restrict__ Wuf, short* __restrict__ Wo0f,
    short* __restrict__ Wn0f, short* __restrict__ Wo1f,
    const int* __restrict__ ei, int* __restrict__ bins,
    int* __restrict__ bsum, int2* __restrict__ sij)
{
  cg::grid_group grid = cg::this_grid();
  __shared__ int s[256];
  const int tid = threadIdx.x;
  const int gidx = blockIdx.x * 256 + tid;
  const int gstride = gridDim.x * 256;

  // phase 0a: weight prep (155,648 items; single pass at 1024 blocks)
  for (int it = gidx; it < 155648; it += gstride)
    wprep_item(it, We, Wm, Ws, Wu, Wo0, Wn0, Wo1,
               Wef, Wmf, Wsf, Wuf, Wo0f, Wn0f, Wo1f);
  // phase 0b: histogram of destinations
  for (int e = gidx; e < NEDGE; e += gstride)
    atomicAdd(&bins[ei[NEDGE + e]], 1);
  grid.sync();

  // phase 1: per-256-segment exclusive scan (first NSEG blocks)
  if (blockIdx.x < NSEG) {
    const int idx = blockIdx.x * 256 + tid;
    int v = (idx < NRES) ? bins[idx] : 0;
    s[tid] = v;
    __syncthreads();
    #pragma unroll
    for (int d = 1; d < 256; d <<= 1) {
      int add = (tid >= d) ? s[tid - d] : 0;
      __syncthreads();
      if (tid >= d) s[tid] += add;
      __syncthreads();
    }
    if (idx < NRES) bins[idx] = s[tid] - v;   // exclusive, block-local
    if (tid == 255) bsum[blockIdx.x] = s[255];
  }
  grid.sync();

  // phase 2: scan the NSEG segment sums (block 0)
  if (blockIdx.x == 0) {
    int v = (tid < NSEG) ? bsum[tid] : 0;
    s[tid] = v;
    __syncthreads();
    #pragma unroll
    for (int d = 1; d < 256; d <<= 1) {
      int add = (tid >= d) ? s[tid - d] : 0;
      __syncthreads();
      if (tid >= d) s[tid] += add;
      __syncthreads();
    }
    if (tid < NSEG) bsum[tid] = s[tid] - v;
  }
  grid.sync();

  // phase 3: payload scatter (bins as cursors + bsum segment base)
  for (int e = gidx; e < NEDGE; e += gstride) {
    int j = ei[e], i = ei[NEDGE + e];
    int slot = atomicAdd(&bins[i], 1) + bsum[i >> 8];
    if (slot >= 0 && slot < NEDGE) sij[slot] = make_int2(j, i);
  }
}

// ---------------------------------------------------------------------------
// standalone sort chain (fallback if cooperative launch unsupported)
__global__ __launch_bounds__(256) void k_wprep(
    const float* __restrict__ We, const float* __restrict__ Wm,
    const float* __restrict__ Ws, const float* __restrict__ Wu,
    const float* __restrict__ Wo0, const float* __restrict__ Wn0,
    const float* __restrict__ Wo1,
    short* __restrict__ Wef, short* __restrict__ Wmf, short* __restrict__ Wsf,
    short* __restrict__ Wuf, short* __restrict__ Wo0f,
    short* __restrict__ Wn0f, short* __restrict__ Wo1f)
{
  int gid = blockIdx.x * 256 + threadIdx.x;
  if (gid < 155648)
    wprep_item(gid, We, Wm, Ws, Wu, Wo0, Wn0, Wo1,
               Wef, Wmf, Wsf, Wuf, Wo0f, Wn0f, Wo1f);
}

__global__ __launch_bounds__(256) void k_hist(
    const int* __restrict__ ei, int* __restrict__ bins)
{
  int e = blockIdx.x * 256 + threadIdx.x;
  if (e < NEDGE) atomicAdd(&bins[ei[NEDGE + e]], 1);
}

__global__ __launch_bounds__(256) void k_scan1(
    int* __restrict__ bins, int* __restrict__ bsum)
{
  __shared__ int s[256];
  const int t = threadIdx.x, b = blockIdx.x;
  const int idx = b * 256 + t;
  int v = (idx < NRES) ? bins[idx] : 0;
  s[t] = v;
  __syncthreads();
  #pragma unroll
  for (int d = 1; d < 256; d <<= 1) {
    int add = (t >= d) ? s[t - d] : 0;
    __syncthreads();
    if (t >= d) s[t] += add;
    __syncthreads();
  }
  if (idx < NRES) bins[idx] = s[t] - v;
  if (t == 255) bsum[b] = s[255];
}

__global__ __launch_bounds__(256) void k_scan2(int* __restrict__ bsum)
{
  __shared__ int s[256];
  const int t = threadIdx.x;
  int v = (t < NSEG) ? bsum[t] : 0;
  s[t] = v;
  __syncthreads();
  #pragma unroll
  for (int d = 1; d < 256; d <<= 1) {
    int add = (t >= d) ? s[t - d] : 0;
    __syncthreads();
    if (t >= d) s[t] += add;
    __syncthreads();
  }
  if (t < NSEG) bsum[t] = s[t] - v;
}

__global__ __launch_bounds__(256) void k_scatter(
    const int* __restrict__ ei, int* __restrict__ bins,
    const int* __restrict__ bsum, int2* __restrict__ sij)
{
  int e = blockIdx.x * 256 + threadIdx.x;
  if (e < NEDGE) {
    int j = ei[e], i = ei[NEDGE + e];
    int slot = atomicAdd(&bins[i], 1) + bsum[i >> 8];
    if (slot >= 0 && slot < NEDGE) sij[slot] = make_int2(j, i);
  }
}

// ---------------------------------------------------------------------------
// FALLBACK x_a -> xb[:,0:64]
__global__ __launch_bounds__(256) void k_xa(
    const int* __restrict__ z, const float* __restrict__ bb,
    const float* __restrict__ side, const float* __restrict__ W_emb,
    const float* __restrict__ b_emb, short* __restrict__ xb)
{
  int tid = threadIdx.x;
  int h = tid & 63;
  int n = blockIdx.x * 4 + (tid >> 6);
  if (n >= NRES) return;
  int zz = z[n];
  float acc = W_emb[zz * 64 + h] + b_emb[h];
  #pragma unroll
  for (int k = 0; k < 6; ++k) acc += bb[n*6 + k] * W_emb[(26 + k)*64 + h];
  #pragma unroll
  for (int k = 0; k < 8; ++k) acc += side[n*8 + k] * W_emb[(32 + k)*64 + h];
  xb[(size_t)n * 128 + h] = f2bf(acc);
}

// ---------------------------------------------------------------------------
// FALLBACK x_s = esm @ W_esm + b -> xb[:,64:128]
__global__ __launch_bounds__(256) void k_esm(
    const float* __restrict__ esm, const short* __restrict__ Wsf,
    const float* __restrict__ b, short* __restrict__ xb)
{
  const int tid = threadIdx.x;
  const int lane = tid & 63, w = tid >> 6;
  const int quad = lane >> 4, colb = lane & 15;
  const int tile0 = blockIdx.x * 64 + w * 16;

  int arow = tile0 + colb;
  if (arow >= NRES) arow = NRES - 1;
  const float* ap = esm + (size_t)arow * 1280 + quad * 8;

  floatx4 acc[4];
  #pragma unroll
  for (int nt = 0; nt < 4; ++nt) acc[nt] = (floatx4){0.f, 0.f, 0.f, 0.f};

  for (int kt = 0; kt < 40; ++kt) {
    float4 v0 = *(const float4*)(ap + kt*32);
    float4 v1 = *(const float4*)(ap + kt*32 + 4);
    short8 a;
    a[0] = f2bf(v0.x); a[1] = f2bf(v0.y); a[2] = f2bf(v0.z); a[3] = f2bf(v0.w);
    a[4] = f2bf(v1.x); a[5] = f2bf(v1.y); a[6] = f2bf(v1.z); a[7] = f2bf(v1.w);
    #pragma unroll
    for (int nt = 0; nt < 4; ++nt) {
      short8 bf = *(const short8*)&Wsf[(size_t)((kt*4 + nt)*64 + lane)*8];
      acc[nt] = __builtin_amdgcn_mfma_f32_16x16x32_bf16(a, bf, acc[nt], 0, 0, 0);
    }
  }
  #pragma unroll
  for (int nt = 0; nt < 4; ++nt) {
    int ch = nt*16 + colb;
    float bias = b[ch];
    #pragma unroll
    for (int r = 0; r < 4; ++r) {
      int n = tile0 + quad*4 + r;
      if (n < NRES) xb[(size_t)n * 128 + 64 + ch] = f2bf(acc[nt][r] + bias);
    }
  }
}

// ---------------------------------------------------------------------------
// FUSED node kernel v3 (R6-proven): LDS-staged esm GEMM, double-buffered,
// two barriers/stage. 512 threads = 8 waves, 64 nodes/block.
__global__ __launch_bounds__(512) void k_node(
    const float* __restrict__ esm, const short* __restrict__ Wsf,
    const float* __restrict__ b_esm,
    const int* __restrict__ z, const float* __restrict__ bb,
    const float* __restrict__ side, const float* __restrict__ W_emb,
    const float* __restrict__ b_emb,
    const short* __restrict__ Wmf,
    short* __restrict__ xb, short* __restrict__ xmb)
{
  __shared__ __align__(16) short sE[2][64][72];  // 18,432 B
  __shared__ __align__(16) short sX[64][136];    // 17,408 B

  const int tid = threadIdx.x;
  const int lane = tid & 63, w = tid >> 6;        // 8 waves
  const int quad = lane >> 4, colb = lane & 15;
  const int n0 = blockIdx.x * 64;

  const int lrow = tid >> 3;
  const int p0 = tid & 7, p1 = p0 + 8;
  int grow = n0 + lrow; if (grow >= NRES) grow = NRES - 1;
  const float* rbase = esm + (size_t)grow * 1280;

  const int rt = w & 3;
  const int ct0 = (w >> 2) * 2, ct1 = ct0 + 1;

  floatx4 acc0 = (floatx4){0.f,0.f,0.f,0.f};
  floatx4 acc1 = (floatx4){0.f,0.f,0.f,0.f};

  {
    float4 va = *(const float4*)(rbase + p0*4);
    float4 vb = *(const float4*)(rbase + p1*4);
    *(unsigned*)&sE[0][lrow][p0*4]     = pkbf(va.x, va.y);
    *(unsigned*)&sE[0][lrow][p0*4 + 2] = pkbf(va.z, va.w);
    *(unsigned*)&sE[0][lrow][p1*4]     = pkbf(vb.x, vb.y);
    *(unsigned*)&sE[0][lrow][p1*4 + 2] = pkbf(vb.z, vb.w);
  }
  __syncthreads();

  for (int s = 0; s < 20; ++s) {
    float4 va = {0.f,0.f,0.f,0.f}, vb = {0.f,0.f,0.f,0.f};
    if (s < 19) {
      va = *(const float4*)(rbase + (s+1)*64 + p0*4);
      vb = *(const float4*)(rbase + (s+1)*64 + p1*4);
    }
    const int buf = s & 1;
    #pragma unroll
    for (int kk = 0; kk < 2; ++kk) {
      short8 af = *(const short8*)&sE[buf][rt*16 + colb][kk*32 + quad*8];
      const int kc = s*2 + kk;
      short8 bf0 = *(const short8*)&Wsf[(size_t)((kc*4 + ct0)*64 + lane)*8];
      short8 bf1 = *(const short8*)&Wsf[(size_t)((kc*4 + ct1)*64 + lane)*8];
      acc0 = __builtin_amdgcn_mfma_f32_16x16x32_bf16(af, bf0, acc0, 0, 0, 0);
      acc1 = __builtin_amdgcn_mfma_f32_16x16x32_bf16(af, bf1, acc1, 0, 0, 0);
    }
    __syncthreads();                 // buf reads done
    if (s < 19) {
      const int nb = (s + 1) & 1;
      *(unsigned*)&sE[nb][lrow][p0*4]     = pkbf(va.x, va.y);
      *(unsigned*)&sE[nb][lrow][p0*4 + 2] = pkbf(va.z, va.w);
      *(unsigned*)&sE[nb][lrow][p1*4]     = pkbf(vb.x, vb.y);
      *(unsigned*)&sE[nb][lrow][p1*4 + 2] = pkbf(vb.z, vb.w);
      __syncthreads();               // next buf ready
    }
  }

  // x_s -> sX[:,64:128]
  {
    float bias0 = b_esm[ct0*16 + colb];
    float bias1 = b_esm[ct1*16 + colb];
    #pragma unroll
    for (int r = 0; r < 4; ++r) {
      int row = rt*16 + quad*4 + r;
      sX[row][64 + ct0*16 + colb] = f2bf(acc0[r] + bias0);
      sX[row][64 + ct1*16 + colb] = f2bf(acc1[r] + bias1);
    }
  }
  // x_a -> sX[:,0:64]
  {
    int r2 = tid >> 3;
    int n2 = n0 + r2; if (n2 >= NRES) n2 = NRES - 1;
    int c0 = (tid & 7) * 8;
    int zz = z[n2];
    float bbv[6], sdv[8];
    #pragma unroll
    for (int k = 0; k < 6; ++k) bbv[k] = bb[n2*6 + k];
    #pragma unroll
    for (int k = 0; k < 8; ++k) sdv[k] = side[n2*8 + k];
    #pragma unroll
    for (int c = 0; c < 8; c += 2) {
      float u0, u1;
      #pragma unroll
      for (int h = 0; h < 2; ++h) {
        int col = c0 + c + h;
        float a2 = W_emb[zz*64 + col] + b_emb[col];
        #pragma unroll
        for (int k = 0; k < 6; ++k) a2 += bbv[k] * W_emb[(26 + k)*64 + col];
        #pragma unroll
        for (int k = 0; k < 8; ++k) a2 += sdv[k] * W_emb[(32 + k)*64 + col];
        if (h) u1 = a2; else u0 = a2;
      }
      *(unsigned*)&sX[r2][c0 + c] = pkbf(u0, u1);
    }
  }
  __syncthreads();

  // xb global write + msg GEMM from sX
  #pragma unroll
  for (int it = 0; it < 2; ++it) {
    int idx = it * 512 + tid;
    int row = idx >> 4, c8 = idx & 15;
    int n = n0 + row;
    if (n < NRES) *(short8*)&xb[(size_t)n * 128 + c8*8] = *(const short8*)&sX[row][c8*8];
  }

  floatx4 accM[4];
  #pragma unroll
  for (int mt = 0; mt < 4; ++mt) accM[mt] = (floatx4){0.f,0.f,0.f,0.f};
  #pragma unroll
  for (int kt = 0; kt < 4; ++kt) {
    short8 b0 = *(const short8*)&Wmf[(size_t)((kt*8 + w)*64 + lane)*8];
    #pragma unroll
    for (int mt = 0; mt < 4; ++mt) {
      short8 a = *(const short8*)&sX[mt*16 + colb][kt*32 + quad*8];
      accM[mt] = __builtin_amdgcn_mfma_f32_16x16x32_bf16(a, b0, accM[mt], 0, 0, 0);
    }
  }
  __syncthreads();   // all sX reads done before overwrite

  // xm -> sX, then coalesced xmb write
  #pragma unroll
  for (int mt = 0; mt < 4; ++mt)
    #pragma unroll
    for (int r = 0; r < 4; ++r)
      sX[mt*16 + quad*4 + r][w*16 + colb] = f2bf(swish_fast(accM[mt][r]));
  __syncthreads();
  #pragma unroll
  for (int it = 0; it < 2; ++it) {
    int idx = it * 512 + tid;
    int row = idx >> 4, c8 = idx & 15;
    int n = n0 + row;
    if (n < NRES) *(short8*)&xmb[(size_t)n * 128 + c8*8] = *(const short8*)&sX[row][c8*8];
  }
}

// ---------------------------------------------------------------------------
// FULL-PATH edge kernel (R6-proven): 64 SORTED edges/block; all 256 threads
// do geometry (4 threads/edge, quarter-split); single GEMM; run-merged scatter.
__global__ __launch_bounds__(256, 4) void k_edge_s(
    const int2* __restrict__ sij,
    const float* __restrict__ pos,
    const float* __restrict__ posn, const float* __restrict__ posc,
    const short* __restrict__ xmb, const short* __restrict__ Wef,
    short* __restrict__ aggb)
{
  __shared__ int sJ[64];
  __shared__ int sI[64];
  __shared__ __align__(16) short sF[64][136];
  __shared__ __align__(16) short sXJ[64][136];

  const int tid = threadIdx.x;
  // bijective XCD swizzle: nwg=15625, 8 XCDs, q=1953, r=1
  const int orig = blockIdx.x;
  const int xcd = orig & 7, sub = orig >> 3;
  const int wg = (xcd == 0 ? 0 : 1954 + (xcd - 1) * 1953) + sub;
  const int e0 = wg * 64;

  if (tid < 64) {
    int2 ji = sij[e0 + tid];
    int jj = ji.x, ii = ji.y;
    sJ[tid] = (jj < 0) ? 0 : ((jj >= NRES) ? NRES - 1 : jj);
    sI[tid] = (ii < 0) ? 0 : ((ii >= NRES) ? NRES - 1 : ii);
  }
  __syncthreads();

  // all threads: geometry for edge tid&63, feature quarter tid>>6
  {
    const int e = tid & 63, q = tid >> 6;
    edge_features_q(e, sJ[e], sI[e], q, pos, posn, posc, sF);
  }
  // all threads: xmb gather for sXJ (4 short8 each)
  #pragma unroll
  for (int it = 0; it < 4; ++it) {
    int idx = it * 256 + tid;
    int row = idx >> 4;
    int c8 = idx & 15;
    *(short8*)&sXJ[row][c8*8] = *(const short8*)&xmb[(size_t)sJ[row] * 128 + c8*8];
  }
  __syncthreads();

  const int lane = tid & 63, w = tid >> 6;
  const int quad = lane >> 4, colb = lane & 15;
  const int nb = w * 2;

  short8 bE[4][2];
  #pragma unroll
  for (int kt = 0; kt < 4; ++kt)
    #pragma unroll
    for (int nt = 0; nt < 2; ++nt)
      bE[kt][nt] = *(const short8*)&Wef[(size_t)((kt*8 + nb + nt)*64 + lane)*8];

  floatx4 accE[4][2];
  #pragma unroll
  for (int mt = 0; mt < 4; ++mt) {
    accE[mt][0] = (floatx4){0.f, 0.f, 0.f, 0.f};
    accE[mt][1] = (floatx4){0.f, 0.f, 0.f, 0.f};
  }

  #pragma unroll
  for (int kt = 0; kt < 4; ++kt) {
    #pragma unroll
    for (int mt = 0; mt < 4; ++mt) {
      short8 af = *(const short8*)&sF[mt*16 + colb][kt*32 + quad*8];
      #pragma unroll
      for (int nt = 0; nt < 2; ++nt)
        accE[mt][nt] = __builtin_amdgcn_mfma_f32_16x16x32_bf16(af, bE[kt][nt], accE[mt][nt], 0, 0, 0);
    }
  }
  __syncthreads();   // all sF reads done; reuse sF as m-staging

  short (*sM)[136] = sF;
  #pragma unroll
  for (int mt = 0; mt < 4; ++mt)
    #pragma unroll
    for (int nt = 0; nt < 2; ++nt) {
      int ch = w*32 + nt*16 + colb;
      #pragma unroll
      for (int r = 0; r < 4; ++r) {
        int e = mt*16 + quad*4 + r;
        float mv = bf2f(sXJ[e][ch]) * swish_fast(accE[mt][nt][r]);
        sM[e][ch] = f2bf(mv);
      }
    }
  __syncthreads();

  // run-merged scatter: edges sorted by i -> one pk-bf16 atomic per run.
  {
    const int p = tid & 63;        // channel pair
    const int g = tid >> 6;        // 16-row group == wave id
    float ax = 0.f, ay = 0.f;
    int cur = sI[g * 16];
    #pragma unroll
    for (int rr = 0; rr < 16; ++rr) {
      int row = g * 16 + rr;
      int ii = sI[row];
      if (ii != cur) {
        bf16x2 v; v[0] = f2bf(ax); v[1] = f2bf(ay);
        atom_pk_bf16(&aggb[(size_t)cur * 128 + p*2], v);
        ax = 0.f; ay = 0.f; cur = ii;
      }
      bf16x2 mv = *(const bf16x2*)&sM[row][p*2];
      ax += bf2f(mv[0]); ay += bf2f(mv[1]);
    }
    bf16x2 v; v[0] = f2bf(ax); v[1] = f2bf(ay);
    atom_pk_bf16(&aggb[(size_t)cur * 128 + p*2], v);
  }
}

// ---------------------------------------------------------------------------
// FALLBACK edge kernel (round-0 baseline): unsorted, two GEMMs,
// per-edge pk-bf16 atomics.
__global__ __launch_bounds__(256, 4) void k_edge_b(
    const int* __restrict__ ei, const float* __restrict__ pos,
    const float* __restrict__ posn, const float* __restrict__ posc,
    const short* __restrict__ xb, const short* __restrict__ Wef,
    const short* __restrict__ Wmf, short* __restrict__ aggb)
{
  __shared__ int sJ[64];
  __shared__ int sI[64];
  __shared__ __align__(16) short sF[64][136];
  __shared__ __align__(16) short sXJ[64][136];

  const int tid = threadIdx.x;
  const int e0 = blockIdx.x * 64;

  if (tid < 64) { sJ[tid] = ei[e0 + tid]; sI[tid] = ei[NEDGE + e0 + tid]; }
  __syncthreads();

  if (tid < 64) {
    edge_features_full(tid, sJ[tid], sI[tid], pos, posn, posc, sF);
  } else {
    const int t2 = tid - 64;
    for (int it = 0; it < 6; ++it) {
      int idx = it * 192 + t2;
      if (idx < 1024) {
        int row = idx >> 4;
        int c8 = idx & 15;
        *(short8*)&sXJ[row][c8*8] = *(const short8*)&xb[(size_t)sJ[row] * 128 + c8*8];
      }
    }
  }
  __syncthreads();

  const int lane = tid & 63, w = tid >> 6;
  const int quad = lane >> 4, colb = lane & 15;
  const int nb = w * 2;

  short8 bE[4][2], bM[4][2];
  #pragma unroll
  for (int kt = 0; kt < 4; ++kt)
    #pragma unroll
    for (int nt = 0; nt < 2; ++nt) {
      bE[kt][nt] = *(const short8*)&Wef[(size_t)((kt*8 + nb + nt)*64 + lane)*8];
      bM[kt][nt] = *(const short8*)&Wmf[(size_t)((kt*8 + nb + nt)*64 + lane)*8];
    }

  floatx4 accE[4][2], accM[4][2];
  #pragma unroll
  for (int mt = 0; mt < 4; ++mt)
    #pragma unroll
    for (int nt = 0; nt < 2; ++nt) {
      accE[mt][nt] = (floatx4){0.f, 0.f, 0.f, 0.f};
      accM[mt][nt] = (floatx4){0.f, 0.f, 0.f, 0.f};
    }

  #pragma unroll
  for (int kt = 0; kt < 4; ++kt) {
    #pragma unroll
    for (int mt = 0; mt < 4; ++mt) {
      short8 af = *(const short8*)&sF [mt*16 + colb][kt*32 + quad*8];
      short8 ax = *(const short8*)&sXJ[mt*16 + colb][kt*32 + quad*8];
      #pragma unroll
      for (int nt = 0; nt < 2; ++nt) {
        accE[mt][nt] = __builtin_amdgcn_mfma_f32_16x16x32_bf16(af, bE[kt][nt], accE[mt][nt], 0, 0, 0);
        accM[mt][nt] = __builtin_amdgcn_mfma_f32_16x16x32_bf16(ax, bM[kt][nt], accM[mt][nt], 0, 0, 0);
      }
    }
  }
  __syncthreads();

  short (*sM)[136] = sXJ;
  #pragma unroll
  for (int mt = 0; mt < 4; ++mt)
    #pragma unroll
    for (int nt = 0; nt < 2; ++nt) {
      int ch = w*32 + nt*16 + colb;
      #pragma unroll
      for (int r = 0; r < 4; ++r) {
        int e = mt*16 + quad*4 + r;
        sM[e][ch] = f2bf(swish_fast(accM[mt][nt][r]) * swish_fast(accE[mt][nt][r]));
      }
    }
  __syncthreads();

  #pragma unroll
  for (int it = 0; it < 16; ++it) {
    int flat = it * 256 + tid;
    int row = flat >> 6, p = flat & 63;
    bf16x2 v = *(const bf16x2*)&sM[row][p*2];
    atom_pk_bf16(&aggb[(size_t)sI[row] * 128 + p*2], v);
  }
}

// ---------------------------------------------------------------------------
// fused update + both heads (R6-proven). 64 nodes/block, 256 threads.
__global__ __launch_bounds__(256) void k_upd(
    const short* __restrict__ xb, const short* __restrict__ aggb,
    const short* __restrict__ Wuf, const short* __restrict__ Wo0f,
    const short* __restrict__ Wn0f, const short* __restrict__ Wo1f,
    const float* __restrict__ bn0, const float* __restrict__ Wnf,
    const float* __restrict__ bnf, const float* __restrict__ bo0,
    const float* __restrict__ bo1, const float* __restrict__ Wof,
    const float* __restrict__ bof, float* __restrict__ out0,
    float* __restrict__ out1)
{
  __shared__ __align__(16) short sA[64][136];
  __shared__ __align__(16) short sX[64][136];
  __shared__ float sS[64][33];

  const int tid = threadIdx.x;
  const int lane = tid & 63, w = tid >> 6;
  const int quad = lane >> 4, colb = lane & 15;
  const int n0 = blockIdx.x * 64;

  #pragma unroll
  for (int it = 0; it < 4; ++it) {
    int idx = it * 256 + tid;
    int row = idx >> 4, c8 = idx & 15;
    int n = n0 + row;
    short8 va = (short8)(short)0, vx = (short8)(short)0;
    if (n < NRES) {
      va = *(const short8*)&aggb[(size_t)n * 128 + c8*8];
      vx = *(const short8*)&xb  [(size_t)n * 128 + c8*8];
    }
    *(short8*)&sA[row][c8*8] = va;
    *(short8*)&sX[row][c8*8] = vx;
  }
  __syncthreads();

  // hn = relu(x@Wn0+bn0); wave w handles mtile w
  {
    floatx4 accN[2];
    accN[0] = (floatx4){0.f,0.f,0.f,0.f}; accN[1] = (floatx4){0.f,0.f,0.f,0.f};
    #pragma unroll
    for (int kt = 0; kt < 4; ++kt) {
      short8 a = *(const short8*)&sX[w*16 + colb][kt*32 + quad*8];
      #pragma unroll
      for (int nt = 0; nt < 2; ++nt) {
        short8 bf = *(const short8*)&Wn0f[(size_t)((kt*2 + nt)*64 + lane)*8];
        accN[nt] = __builtin_amdgcn_mfma_f32_16x16x32_bf16(a, bf, accN[nt], 0, 0, 0);
      }
    }
    #pragma unroll
    for (int nt = 0; nt < 2; ++nt) {
      int col = nt*16 + colb;
      float bias = bn0[col];
      #pragma unroll
      for (int r = 0; r < 4; ++r)
        sS[w*16 + quad*4 + r][col] = fmaxf(accN[nt][r] + bias, 0.0f);
    }
  }
  __syncthreads();
  if (tid < 128) {
    int row = tid >> 1, oc = tid & 1;
    int n = n0 + row;
    if (n < NRES) {
      float a2 = bnf[oc];
      #pragma unroll
      for (int k = 0; k < 32; ++k) a2 += sS[row][k] * Wnf[k*2 + oc];
      out1[(size_t)n * 2 + oc] = a2;
    }
  }

  // GEMM1: t = agg@Wu
  floatx4 acc1[4][2];
  #pragma unroll
  for (int mt = 0; mt < 4; ++mt) {
    acc1[mt][0] = (floatx4){0.f,0.f,0.f,0.f};
    acc1[mt][1] = (floatx4){0.f,0.f,0.f,0.f};
  }
  #pragma unroll
  for (int kt = 0; kt < 4; ++kt) {
    short8 b0 = *(const short8*)&Wuf[(size_t)((kt*8 + w*2 + 0)*64 + lane)*8];
    short8 b1 = *(const short8*)&Wuf[(size_t)((kt*8 + w*2 + 1)*64 + lane)*8];
    #pragma unroll
    for (int mt = 0; mt < 4; ++mt) {
      short8 a = *(const short8*)&sA[mt*16 + colb][kt*32 + quad*8];
      acc1[mt][0] = __builtin_amdgcn_mfma_f32_16x16x32_bf16(a, b0, acc1[mt][0], 0, 0, 0);
      acc1[mt][1] = __builtin_amdgcn_mfma_f32_16x16x32_bf16(a, b1, acc1[mt][1], 0, 0, 0);
    }
  }
  __syncthreads();
  // xe = x + swish(t)
  #pragma unroll
  for (int mt = 0; mt < 4; ++mt)
    #pragma unroll
    for (int nt = 0; nt < 2; ++nt)
      #pragma unroll
      for (int r = 0; r < 4; ++r) {
        int row = mt*16 + quad*4 + r, col = w*32 + nt*16 + colb;
        float xv = bf2f(sX[row][col]);
        sA[row][col] = f2bf(xv + swish_fast(acc1[mt][nt][r]));
      }
  __syncthreads();

  // GEMM2: h = relu(xe@Wo0 + bo0)
  floatx4 acc2[4][2];
  #pragma unroll
  for (int mt = 0; mt < 4; ++mt) {
    acc2[mt][0] = (floatx4){0.f,0.f,0.f,0.f};
    acc2[mt][1] = (floatx4){0.f,0.f,0.f,0.f};
  }
  #pragma unroll
  for (int kt = 0; kt < 4; ++kt) {
    short8 b0 = *(const short8*)&Wo0f[(size_t)((kt*8 + w*2 + 0)*64 + lane)*8];
    short8 b1 = *(const short8*)&Wo0f[(size_t)((kt*8 + w*2 + 1)*64 + lane)*8];
    #pragma unroll
    for (int mt = 0; mt < 4; ++mt) {
      short8 a = *(const short8*)&sA[mt*16 + colb][kt*32 + quad*8];
      acc2[mt][0] = __builtin_amdgcn_mfma_f32_16x16x32_bf16(a, b0, acc2[mt][0], 0, 0, 0);
      acc2[mt][1] = __builtin_amdgcn_mfma_f32_16x16x32_bf16(a, b1, acc2[mt][1], 0, 0, 0);
    }
  }
  __syncthreads();
  #pragma unroll
  for (int mt = 0; mt < 4; ++mt)
    #pragma unroll
    for (int nt = 0; nt < 2; ++nt) {
      int col = w*32 + nt*16 + colb;
      float bias = bo0[col];
      #pragma unroll
      for (int r = 0; r < 4; ++r) {
        int row = mt*16 + quad*4 + r;
        sX[row][col] = f2bf(fmaxf(acc2[mt][nt][r] + bias, 0.0f));
      }
    }
  __syncthreads();

  // GEMM3: h2 = relu(h@Wo1 + bo1); wave w handles mtile w
  {
    floatx4 accH[2];
    accH[0] = (floatx4){0.f,0.f,0.f,0.f}; accH[1] = (floatx4){0.f,0.f,0.f,0.f};
    #pragma unroll
    for (int kt = 0; kt < 4; ++kt) {
      short8 a = *(const short8*)&sX[w*16 + colb][kt*32 + quad*8];
      #pragma unroll
      for (int nt = 0; nt < 2; ++nt) {
        short8 bf = *(const short8*)&Wo1f[(size_t)((kt*2 + nt)*64 + lane)*8];
        accH[nt] = __builtin_amdgcn_mfma_f32_16x16x32_bf16(a, bf, accH[nt], 0, 0, 0);
      }
    }
    __syncthreads();
    #pragma unroll
    for (int nt = 0; nt < 2; ++nt) {
      int col = nt*16 + colb;
      float bias = bo1[col];
      #pragma unroll
      for (int r = 0; r < 4; ++r)
        sS[w*16 + quad*4 + r][col] = fmaxf(accH[nt][r] + bias, 0.0f);
    }
  }
  __syncthreads();

  if (tid < 64) {
    int n = n0 + tid;
    if (n < NRES) {
      float a2 = bof[0];
      #pragma unroll
      for (int k = 0; k < 32; ++k) a2 += sS[tid][k] * Wof[k];
      out0[n] = 1.0f / (1.0f + expf(-a2));
    }
  }
}

// ---------------------------------------------------------------------------
extern "C" void kernel_launch(void* const* d_in, const int* in_sizes, int n_in,
                              void* d_out, int out_size, void* d_ws, size_t ws_size,
                              hipStream_t stream) {
  (void)in_sizes; (void)n_in; (void)out_size;
  const int*   z     = (const int*)  d_in[0];
  const float* pos   = (const float*)d_in[1];
  const float* posn  = (const float*)d_in[2];
  const float* posc  = (const float*)d_in[3];
  const float* bb    = (const float*)d_in[4];
  const float* side  = (const float*)d_in[5];
  const float* esm   = (const float*)d_in[6];
  const int*   ei    = (const int*)  d_in[8];
  const float* W_emb = (const float*)d_in[9];
  const float* b_emb = (const float*)d_in[10];
  const float* W_esm = (const float*)d_in[11];
  const float* b_esm = (const float*)d_in[12];
  const float* W_edge= (const float*)d_in[13];
  const float* W_msg = (const float*)d_in[14];
  const float* W_upd = (const float*)d_in[15];
  const float* W_o0  = (const float*)d_in[16];
  const float* b_o0  = (const float*)d_in[17];
  const float* W_o1  = (const float*)d_in[18];
  const float* b_o1  = (const float*)d_in[19];
  const float* W_of  = (const float*)d_in[20];
  const float* b_of  = (const float*)d_in[21];
  const float* W_n0  = (const float*)d_in[22];
  const float* b_n0  = (const float*)d_in[23];
  const float* W_nf  = (const float*)d_in[24];
  const float* b_nf  = (const float*)d_in[25];

  float* out0 = (float*)d_out;                         // [N]
  float* out1 = out0 + NRES;                           // [N,2]
  char* ws = (char*)d_ws;

  const bool full = (ws_size >= (size_t)46912096);

  if (full) {
    // ---- full layout (~46.9 MB) ----
    short* xb   = (short*)ws;                          // 12,800,000 B
    short* aggb = (short*)(ws + 12800000);             // 12,800,000 B
    short* xmb  = (short*)(ws + 25600000);             // 12,800,000 B
    short* Wef  = (short*)(ws + 38400000);             // 32,768 B
    short* Wmf  = (short*)(ws + 38432768);             // 32,768 B
    short* Wsf  = (short*)(ws + 38465536);             // 163,840 B
    short* Wuf  = (short*)(ws + 38629376);             // 32,768 B
    short* Wo0f = (short*)(ws + 38662144);             // 32,768 B
    short* Wn0f = (short*)(ws + 38694912);             // 8,192 B
    short* Wo1f = (short*)(ws + 38703104);             // 8,192 B
    int*   bins = (int*)  (ws + 38711296);             // 200,000 B
    int*   bsum = (int*)  (ws + 38911296);             // 800 B
    int2*  sij  = (int2*) (ws + 38912096);             // 8,000,000 B

    hipMemsetAsync(aggb, 0, (size_t)NRES * 128 * sizeof(short), stream);
    hipMemsetAsync(bins, 0, (size_t)NRES * sizeof(int), stream);

    // cooperative fused sort (wprep+hist | scan1 | scan2 | scatter)
    void* ca[] = {
      (void*)&W_edge, (void*)&W_msg, (void*)&W_esm, (void*)&W_upd,
      (void*)&W_o0, (void*)&W_n0, (void*)&W_o1,
      (void*)&Wef, (void*)&Wmf, (void*)&Wsf, (void*)&Wuf,
      (void*)&Wo0f, (void*)&Wn0f, (void*)&Wo1f,
      (void*)&ei, (void*)&bins, (void*)&bsum, (void*)&sij
    };
    hipError_t cerr = hipLaunchCooperativeKernel(
        (const void*)k_sort_coop, dim3(1024), dim3(256), ca, 0, stream);
    if (cerr != hipSuccess) {
      (void)hipGetLastError();   // clear sticky error, use split chain
      k_wprep  <<<608, 256, 0, stream>>>(W_edge, W_msg, W_esm, W_upd, W_o0,
                                         W_n0, W_o1, Wef, Wmf, Wsf, Wuf,
                                         Wo0f, Wn0f, Wo1f);
      k_hist   <<<3907, 256, 0, stream>>>(ei, bins);
      k_scan1  <<<NSEG, 256, 0, stream>>>(bins, bsum);
      k_scan2  <<<1,    256, 0, stream>>>(bsum);
      k_scatter<<<3907, 256, 0, stream>>>(ei, bins, bsum, sij);
    }

    k_node   <<<782,  512, 0, stream>>>(esm, Wsf, b_esm, z, bb, side, W_emb, b_emb,
                                        Wmf, xb, xmb);
    k_edge_s <<<15625, 256, 0, stream>>>(sij, pos, posn, posc, xmb, Wef, aggb);
    k_upd    <<<782,   256, 0, stream>>>(xb, aggb, Wuf, Wo0f, Wn0f, Wo1f,
                                         b_n0, W_nf, b_nf, b_o0, b_o1, W_of, b_of,
                                         out0, out1);
  } else {
    // ---- fallback: round-0 proven layout (25.9 MB) ----
    short* xb   = (short*)ws;                          // 12,800,000 B
    short* aggb = (short*)(ws + 12800000);             // 12,800,000 B
    short* Wef  = (short*)(ws + 25600000);             // 32,768 B
    short* Wmf  = (short*)(ws + 25632768);             // 32,768 B
    short* Wsf  = (short*)(ws + 25665536);             // 163,840 B
    short* Wuf  = (short*)(ws + 25829376);             // 32,768 B
    short* Wo0f = (short*)(ws + 25862144);             // 32,768 B
    short* Wn0f = (short*)(ws + 25894912);             // 8,192 B
    short* Wo1f = (short*)(ws + 25903104);             // 8,192 B

    hipMemsetAsync(aggb, 0, (size_t)NRES * 128 * sizeof(short), stream);

    k_wprep <<<608, 256, 0, stream>>>(W_edge, W_msg, W_esm, W_upd, W_o0, W_n0, W_o1,
                                      Wef, Wmf, Wsf, Wuf, Wo0f, Wn0f, Wo1f);
    k_xa    <<<12500, 256, 0, stream>>>(z, bb, side, W_emb, b_emb, xb);
    k_esm   <<<782,   256, 0, stream>>>(esm, Wsf, b_esm, xb);
    k_edge_b<<<15625, 256, 0, stream>>>(ei, pos, posn, posc, xb, Wef, Wmf, aggb);
    k_upd   <<<782,   256, 0, stream>>>(xb, aggb, Wuf, Wo0f, Wn0f, Wo1f,
                                        b_n0, W_nf, b_nf, b_o0, b_o1, W_of, b_of,
                                        out0, out1);
  }
}

// Round 11
// 673.203 us; speedup vs baseline: 1.5360x; 1.5360x over previous
//
#include <hip/hip_runtime.h>
#include <math.h>
#include <stdint.h>

#define NRES 50000
#define NEDGE 1000000
#define PI_F 3.14159265358979323846f
#define NSEG 196   // ceil(NRES/256)

typedef __attribute__((ext_vector_type(8))) short short8;
typedef __attribute__((ext_vector_type(4))) float floatx4;
typedef __attribute__((ext_vector_type(2))) short bf16x2;
typedef __attribute__((address_space(1))) bf16x2* gbf16x2p;

struct f3 { float x, y, z; };
__device__ __forceinline__ f3 ld3(const float* __restrict__ p, int i) {
  return {p[3*i+0], p[3*i+1], p[3*i+2]};
}
__device__ __forceinline__ f3 f3sub(f3 a, f3 b){ return {a.x-b.x, a.y-b.y, a.z-b.z}; }
__device__ __forceinline__ f3 f3cross(f3 a, f3 b){
  return {a.y*b.z - a.z*b.y, a.z*b.x - a.x*b.z, a.x*b.y - a.y*b.x};
}
__device__ __forceinline__ float f3dot(f3 a, f3 b){ return a.x*b.x + a.y*b.y + a.z*b.z; }
__device__ __forceinline__ float swish_fast(float v){
  return v * __builtin_amdgcn_rcpf(1.0f + __expf(-v));
}
__device__ __forceinline__ short f2bf(float f){
  unsigned u = __float_as_uint(f);
  unsigned r = (u + 0x7fffu + ((u >> 16) & 1u)) >> 16;
  return (short)r;
}
__device__ __forceinline__ float bf2f(short s){
  return __uint_as_float(((unsigned)(unsigned short)s) << 16);
}
__device__ __forceinline__ float cos_atan2(float y, float x){
  return x * __builtin_amdgcn_rsqf(fmaxf(x*x + y*y, 1e-30f));
}
__device__ __forceinline__ void atom_pk_bf16(short* addr, bf16x2 v){
  __builtin_amdgcn_global_atomic_fadd_v2bf16((gbf16x2p)(uintptr_t)addr, v);
}
// packed f32x2 -> bf16x2 (RNE) in one instruction
__device__ __forceinline__ unsigned pkbf(float lo, float hi){
  unsigned r;
  asm("v_cvt_pk_bf16_f32 %0, %1, %2" : "=v"(r) : "v"(lo), "v"(hi));
  return r;
}

// ---------------------------------------------------------------------------
// geometry scalars for one edge (shared)
struct EdgeGeo {
  float rb[6];
  float ct, cp, ca1, ca2, ca3;
  float dpe;
};
__device__ __forceinline__ EdgeGeo edge_geo(
    int j, int i,
    const float* __restrict__ pos, const float* __restrict__ posn,
    const float* __restrict__ posc)
{
  EdgeGeo g;
  f3 pj = ld3(pos, j), pi = ld3(pos, i);
  f3 vji = f3sub(pj, pi);
  float nji2 = f3dot(vji, vji);
  float dist = sqrtf(nji2);
  int r0i = (i == 0) ? (NRES - 1) : (i - 1);
  int r1i = (i == NRES - 1) ? 0 : (i + 1);
  f3 vr0 = f3sub(ld3(pos, r0i), pi);
  f3 vr1 = f3sub(ld3(pos, r1i), pi);
  float nr02 = f3dot(vr0, vr0);

  g.ct = f3dot(vji, vr0) * __builtin_amdgcn_rsqf(fmaxf(nji2 * nr02, 1e-30f));
  f3 p1 = f3cross(vr0, vr1);
  f3 p2 = f3cross(vr0, vji);
  float pa = f3dot(p1, p2);
  float pb = f3dot(f3cross(p1, p2), vr0) / (sqrtf(nr02) + 1e-7f);
  g.cp = cos_atan2(pb, pa);

  f3 pni = ld3(posn, i), pci = ld3(posc, i);
  f3 o1x = f3sub(pni, pi);
  f3 o1z = f3cross(o1x, f3cross(o1x, f3sub(pci, pi)));
  float no1z2 = f3dot(o1z, o1z);
  float o1zl = sqrtf(no1z2) + 1e-7f;
  f3 pnj = ld3(posn, j), pcj = ld3(posc, j);
  f3 o2x = f3sub(pnj, pj);
  f3 o2z = f3cross(o2x, f3cross(o2x, f3sub(pcj, pj)));
  float no2z2 = f3dot(o2z, o2z);
  float o2zl = sqrtf(no2z2) + 1e-7f;
  f3 nv = f3cross(o1z, o2z);
  float y1 = f3dot(f3cross(o1x, nv), o1z) / o1zl;
  g.ca1 = cos_atan2(y1, f3dot(o1x, nv));
  g.ca2 = f3dot(o1z, o2z) * __builtin_amdgcn_rsqf(fmaxf(no1z2 * no2z2, 1e-30f));
  float y3 = f3dot(f3cross(nv, o2x), o2z) / o2zl;
  g.ca3 = cos_atan2(y3, f3dot(nv, o2x));

  float u = fminf(dist * (1.0f/11.5f), 1.0f);
  float spu, cpu;
  __sincosf(PI_F * u, &spu, &cpu);
  float fc = 0.5f * (cpu + 1.0f);
  float pref = 0.41702882811414954f * __builtin_amdgcn_rcpf(dist + 1e-6f) * fc;
  {
    float twoc = 2.0f * cpu;
    float s_nm1 = 0.0f, s_n = spu;
    #pragma unroll
    for (int nn = 0; nn < 6; ++nn) {
      g.rb[nn] = pref * s_n;
      float s_np1 = twoc * s_n - s_nm1;
      s_nm1 = s_n; s_n = s_np1;
    }
  }
  g.dpe = (float)(j - i);
  return g;
}

// feature value at position f (0..107), compile-time f
__device__ __forceinline__ float feat_val(const EdgeGeo& g, int f,
                                          const float* ctv, const float* cpv,
                                          const float* cav1, const float* cav2,
                                          const float* cav3)
{
  if (f < 54) {
    int nn = f / 9, l = (f % 9) / 3, m = f % 3;
    return g.rb[nn] * ctv[l] * cpv[m];
  } else {
    int ff = f - 54;
    int t = ff / 18, nn = (ff % 18) / 3, l = ff % 3;
    const float* cav = (t == 0) ? cav1 : (t == 1) ? cav2 : cav3;
    return g.rb[nn] * cav[l];
  }
}

// quarter-split feature pack: 4 threads per edge (quarter q), redundant
// geometry, each writes a disjoint pair-aligned slice. (R6-proven)
__device__ __forceinline__ void edge_features_q(
    int e, int j, int i, int q,
    const float* __restrict__ pos, const float* __restrict__ posn,
    const float* __restrict__ posc, short (*sF)[136])
{
  EdgeGeo g = edge_geo(j, i, pos, posn, posc);
  float ctv[3]  = {1.0f, g.ct,  2.0f*g.ct*g.ct  - 1.0f};
  float cpv[3]  = {1.0f, g.cp,  2.0f*g.cp*g.cp  - 1.0f};
  float cav1[3] = {1.0f, g.ca1, 2.0f*g.ca1*g.ca1 - 1.0f};
  float cav2[3] = {1.0f, g.ca2, 2.0f*g.ca2*g.ca2 - 1.0f};
  float cav3[3] = {1.0f, g.ca3, 2.0f*g.ca3*g.ca3 - 1.0f};

  if (q == 0) {
    #pragma unroll
    for (int f = 0; f < 28; f += 2)
      *(unsigned*)&sF[e][f] = pkbf(feat_val(g, f, ctv, cpv, cav1, cav2, cav3),
                                   feat_val(g, f+1, ctv, cpv, cav1, cav2, cav3));
  } else if (q == 1) {
    #pragma unroll
    for (int f = 28; f < 54; f += 2)
      *(unsigned*)&sF[e][f] = pkbf(feat_val(g, f, ctv, cpv, cav1, cav2, cav3),
                                   feat_val(g, f+1, ctv, cpv, cav1, cav2, cav3));
    const float FRQ[8] = {1.0f, 0.31622776601683794f, 0.1f, 0.03162277660168379f,
                          0.01f, 0.003162277660168379f, 0.001f, 0.0003162277660168379f};
    float cb[8], sb[8];
    #pragma unroll
    for (int p = 0; p < 8; ++p) __sincosf(g.dpe * FRQ[p], &sb[p], &cb[p]);
    #pragma unroll
    for (int p = 0; p < 8; p += 2) {
      *(unsigned*)&sF[e][108 + p] = pkbf(cb[p], cb[p+1]);
      *(unsigned*)&sF[e][116 + p] = pkbf(sb[p], sb[p+1]);
    }
    *(unsigned*)&sF[e][124] = 0u;
    *(unsigned*)&sF[e][126] = 0u;
  } else if (q == 2) {
    #pragma unroll
    for (int f = 54; f < 80; f += 2)
      *(unsigned*)&sF[e][f] = pkbf(feat_val(g, f, ctv, cpv, cav1, cav2, cav3),
                                   feat_val(g, f+1, ctv, cpv, cav1, cav2, cav3));
  } else {
    #pragma unroll
    for (int f = 80; f < 108; f += 2)
      *(unsigned*)&sF[e][f] = pkbf(feat_val(g, f, ctv, cpv, cav1, cav2, cav3),
                                   feat_val(g, f+1, ctv, cpv, cav1, cav2, cav3));
  }
}

// full-row feature pack (used by fallback edge kernel): one thread per edge
__device__ __forceinline__ void edge_features_full(
    int e, int j, int i,
    const float* __restrict__ pos, const float* __restrict__ posn,
    const float* __restrict__ posc, short (*sF)[136])
{
  EdgeGeo g = edge_geo(j, i, pos, posn, posc);
  float ctv[3]  = {1.0f, g.ct,  2.0f*g.ct*g.ct  - 1.0f};
  float cpv[3]  = {1.0f, g.cp,  2.0f*g.cp*g.cp  - 1.0f};
  float cav1[3] = {1.0f, g.ca1, 2.0f*g.ca1*g.ca1 - 1.0f};
  float cav2[3] = {1.0f, g.ca2, 2.0f*g.ca2*g.ca2 - 1.0f};
  float cav3[3] = {1.0f, g.ca3, 2.0f*g.ca3*g.ca3 - 1.0f};
  #pragma unroll
  for (int f = 0; f < 108; f += 2) {
    float v0 = feat_val(g, f,     ctv, cpv, cav1, cav2, cav3);
    float v1 = feat_val(g, f + 1, ctv, cpv, cav1, cav2, cav3);
    *(unsigned*)&sF[e][f] = pkbf(v0, v1);
  }
  const float FRQ[8] = {1.0f, 0.31622776601683794f, 0.1f, 0.03162277660168379f,
                        0.01f, 0.003162277660168379f, 0.001f, 0.0003162277660168379f};
  float cb[8], sb[8];
  #pragma unroll
  for (int q = 0; q < 8; ++q) __sincosf(g.dpe * FRQ[q], &sb[q], &cb[q]);
  #pragma unroll
  for (int q = 0; q < 8; q += 2) {
    *(unsigned*)&sF[e][108 + q] = pkbf(cb[q], cb[q+1]);
    *(unsigned*)&sF[e][116 + q] = pkbf(sb[q], sb[q+1]);
  }
  *(unsigned*)&sF[e][124] = 0u;
  *(unsigned*)&sF[e][126] = 0u;
}

// ---------------------------------------------------------------------------
// weight prep -> bf16 MFMA B-fragment order.
__global__ __launch_bounds__(256) void k_wprep(
    const float* __restrict__ We, const float* __restrict__ Wm,
    const float* __restrict__ Ws, const float* __restrict__ Wu,
    const float* __restrict__ Wo0, const float* __restrict__ Wn0,
    const float* __restrict__ Wo1,
    short* __restrict__ Wef, short* __restrict__ Wmf, short* __restrict__ Wsf,
    short* __restrict__ Wuf, short* __restrict__ Wo0f,
    short* __restrict__ Wn0f, short* __restrict__ Wo1f)
{
  int gid = blockIdx.x * 256 + threadIdx.x;
  const float* src; short* dst; int NT, K, N, t;
  if      (gid < 16384)  { t = gid;          src = We;  dst = Wef;  NT = 8; K = 124;  N = 128; }
  else if (gid < 32768)  { t = gid - 16384;  src = Wm;  dst = Wmf;  NT = 8; K = 128;  N = 128; }
  else if (gid < 114688) { t = gid - 32768;  src = Ws;  dst = Wsf;  NT = 4; K = 1280; N = 64;  }
  else if (gid < 131072) { t = gid - 114688; src = Wu;  dst = Wuf;  NT = 8; K = 128;  N = 128; }
  else if (gid < 147456) { t = gid - 131072; src = Wo0; dst = Wo0f; NT = 8; K = 128;  N = 128; }
  else if (gid < 151552) { t = gid - 147456; src = Wn0; dst = Wn0f; NT = 2; K = 128;  N = 32;  }
  else if (gid < 155648) { t = gid - 151552; src = Wo1; dst = Wo1f; NT = 2; K = 128;  N = 32;  }
  else return;
  int j = t & 7, lane = (t >> 3) & 63;
  int rest = t >> 9;
  int nt = rest % NT, kt = rest / NT;
  int k = kt*32 + (lane >> 4)*8 + j, n = nt*16 + (lane & 15);
  dst[t] = f2bf((k < K) ? src[k*N + n] : 0.0f);
}

// ---------------------------------------------------------------------------
// counting-sort of edges by destination i: histogram
__global__ __launch_bounds__(256) void k_hist(
    const int* __restrict__ ei, int* __restrict__ bins)
{
  int e = blockIdx.x * 256 + threadIdx.x;
  if (e < NEDGE) atomicAdd(&bins[ei[NEDGE + e]], 1);
}

// exclusive scan, level 1: per-256 block (in place), emit block sums
__global__ __launch_bounds__(256) void k_scan1(
    int* __restrict__ bins, int* __restrict__ bsum)
{
  __shared__ int s[256];
  const int t = threadIdx.x, b = blockIdx.x;
  const int idx = b * 256 + t;
  int v = (idx < NRES) ? bins[idx] : 0;
  s[t] = v;
  __syncthreads();
  #pragma unroll
  for (int d = 1; d < 256; d <<= 1) {
    int add = (t >= d) ? s[t - d] : 0;
    __syncthreads();
    if (t >= d) s[t] += add;
    __syncthreads();
  }
  if (idx < NRES) bins[idx] = s[t] - v;   // exclusive, block-local
  if (t == 255) bsum[b] = s[255];
}

// level 2: scan the NSEG block sums (single block, in place, exclusive)
__global__ __launch_bounds__(256) void k_scan2(int* __restrict__ bsum)
{
  __shared__ int s[256];
  const int t = threadIdx.x;
  int v = (t < NSEG) ? bsum[t] : 0;
  s[t] = v;
  __syncthreads();
  #pragma unroll
  for (int d = 1; d < 256; d <<= 1) {
    int add = (t >= d) ? s[t - d] : 0;
    __syncthreads();
    if (t >= d) s[t] += add;
    __syncthreads();
  }
  if (t < NSEG) bsum[t] = s[t] - v;
}

// scatter edge PAYLOAD (j,i) into sorted order; global offset folded in
// (slot = block-local scan cursor + bsum[i>>8]).
__global__ __launch_bounds__(256) void k_scatter(
    const int* __restrict__ ei, int* __restrict__ bins,
    const int* __restrict__ bsum, int2* __restrict__ sij)
{
  int e = blockIdx.x * 256 + threadIdx.x;
  if (e < NEDGE) {
    int j = ei[e], i = ei[NEDGE + e];
    int slot = atomicAdd(&bins[i], 1) + bsum[i >> 8];
    if (slot >= 0 && slot < NEDGE) sij[slot] = make_int2(j, i);
  }
}

// ---------------------------------------------------------------------------
// FALLBACK x_a -> xb[:,0:64]
__global__ __launch_bounds__(256) void k_xa(
    const int* __restrict__ z, const float* __restrict__ bb,
    const float* __restrict__ side, const float* __restrict__ W_emb,
    const float* __restrict__ b_emb, short* __restrict__ xb)
{
  int tid = threadIdx.x;
  int h = tid & 63;
  int n = blockIdx.x * 4 + (tid >> 6);
  if (n >= NRES) return;
  int zz = z[n];
  float acc = W_emb[zz * 64 + h] + b_emb[h];
  #pragma unroll
  for (int k = 0; k < 6; ++k) acc += bb[n*6 + k] * W_emb[(26 + k)*64 + h];
  #pragma unroll
  for (int k = 0; k < 8; ++k) acc += side[n*8 + k] * W_emb[(32 + k)*64 + h];
  xb[(size_t)n * 128 + h] = f2bf(acc);
}

// ---------------------------------------------------------------------------
// FALLBACK x_s = esm @ W_esm + b -> xb[:,64:128]
__global__ __launch_bounds__(256) void k_esm(
    const float* __restrict__ esm, const short* __restrict__ Wsf,
    const float* __restrict__ b, short* __restrict__ xb)
{
  const int tid = threadIdx.x;
  const int lane = tid & 63, w = tid >> 6;
  const int quad = lane >> 4, colb = lane & 15;
  const int tile0 = blockIdx.x * 64 + w * 16;

  int arow = tile0 + colb;
  if (arow >= NRES) arow = NRES - 1;
  const float* ap = esm + (size_t)arow * 1280 + quad * 8;

  floatx4 acc[4];
  #pragma unroll
  for (int nt = 0; nt < 4; ++nt) acc[nt] = (floatx4){0.f, 0.f, 0.f, 0.f};

  for (int kt = 0; kt < 40; ++kt) {
    float4 v0 = *(const float4*)(ap + kt*32);
    float4 v1 = *(const float4*)(ap + kt*32 + 4);
    short8 a;
    a[0] = f2bf(v0.x); a[1] = f2bf(v0.y); a[2] = f2bf(v0.z); a[3] = f2bf(v0.w);
    a[4] = f2bf(v1.x); a[5] = f2bf(v1.y); a[6] = f2bf(v1.z); a[7] = f2bf(v1.w);
    #pragma unroll
    for (int nt = 0; nt < 4; ++nt) {
      short8 bf = *(const short8*)&Wsf[(size_t)((kt*4 + nt)*64 + lane)*8];
      acc[nt] = __builtin_amdgcn_mfma_f32_16x16x32_bf16(a, bf, acc[nt], 0, 0, 0);
    }
  }
  #pragma unroll
  for (int nt = 0; nt < 4; ++nt) {
    int ch = nt*16 + colb;
    float bias = b[ch];
    #pragma unroll
    for (int r = 0; r < 4; ++r) {
      int n = tile0 + quad*4 + r;
      if (n < NRES) xb[(size_t)n * 128 + 64 + ch] = f2bf(acc[nt][r] + bias);
    }
  }
}

// ---------------------------------------------------------------------------
// FUSED node kernel v3 (R6-proven): LDS-staged esm GEMM, double-buffered,
// two barriers/stage. 512 threads = 8 waves, 64 nodes/block.
__global__ __launch_bounds__(512) void k_node(
    const float* __restrict__ esm, const short* __restrict__ Wsf,
    const float* __restrict__ b_esm,
    const int* __restrict__ z, const float* __restrict__ bb,
    const float* __restrict__ side, const float* __restrict__ W_emb,
    const float* __restrict__ b_emb,
    const short* __restrict__ Wmf,
    short* __restrict__ xb, short* __restrict__ xmb)
{
  __shared__ __align__(16) short sE[2][64][72];  // 18,432 B
  __shared__ __align__(16) short sX[64][136];    // 17,408 B

  const int tid = threadIdx.x;
  const int lane = tid & 63, w = tid >> 6;        // 8 waves
  const int quad = lane >> 4, colb = lane & 15;
  const int n0 = blockIdx.x * 64;

  const int lrow = tid >> 3;
  const int p0 = tid & 7, p1 = p0 + 8;
  int grow = n0 + lrow; if (grow >= NRES) grow = NRES - 1;
  const float* rbase = esm + (size_t)grow * 1280;

  const int rt = w & 3;
  const int ct0 = (w >> 2) * 2, ct1 = ct0 + 1;

  floatx4 acc0 = (floatx4){0.f,0.f,0.f,0.f};
  floatx4 acc1 = (floatx4){0.f,0.f,0.f,0.f};

  {
    float4 va = *(const float4*)(rbase + p0*4);
    float4 vb = *(const float4*)(rbase + p1*4);
    *(unsigned*)&sE[0][lrow][p0*4]     = pkbf(va.x, va.y);
    *(unsigned*)&sE[0][lrow][p0*4 + 2] = pkbf(va.z, va.w);
    *(unsigned*)&sE[0][lrow][p1*4]     = pkbf(vb.x, vb.y);
    *(unsigned*)&sE[0][lrow][p1*4 + 2] = pkbf(vb.z, vb.w);
  }
  __syncthreads();

  for (int s = 0; s < 20; ++s) {
    float4 va = {0.f,0.f,0.f,0.f}, vb = {0.f,0.f,0.f,0.f};
    if (s < 19) {
      va = *(const float4*)(rbase + (s+1)*64 + p0*4);
      vb = *(const float4*)(rbase + (s+1)*64 + p1*4);
    }
    const int buf = s & 1;
    #pragma unroll
    for (int kk = 0; kk < 2; ++kk) {
      short8 af = *(const short8*)&sE[buf][rt*16 + colb][kk*32 + quad*8];
      const int kc = s*2 + kk;
      short8 bf0 = *(const short8*)&Wsf[(size_t)((kc*4 + ct0)*64 + lane)*8];
      short8 bf1 = *(const short8*)&Wsf[(size_t)((kc*4 + ct1)*64 + lane)*8];
      acc0 = __builtin_amdgcn_mfma_f32_16x16x32_bf16(af, bf0, acc0, 0, 0, 0);
      acc1 = __builtin_amdgcn_mfma_f32_16x16x32_bf16(af, bf1, acc1, 0, 0, 0);
    }
    __syncthreads();                 // buf reads done
    if (s < 19) {
      const int nb = (s + 1) & 1;
      *(unsigned*)&sE[nb][lrow][p0*4]     = pkbf(va.x, va.y);
      *(unsigned*)&sE[nb][lrow][p0*4 + 2] = pkbf(va.z, va.w);
      *(unsigned*)&sE[nb][lrow][p1*4]     = pkbf(vb.x, vb.y);
      *(unsigned*)&sE[nb][lrow][p1*4 + 2] = pkbf(vb.z, vb.w);
      __syncthreads();               // next buf ready
    }
  }

  // x_s -> sX[:,64:128]
  {
    float bias0 = b_esm[ct0*16 + colb];
    float bias1 = b_esm[ct1*16 + colb];
    #pragma unroll
    for (int r = 0; r < 4; ++r) {
      int row = rt*16 + quad*4 + r;
      sX[row][64 + ct0*16 + colb] = f2bf(acc0[r] + bias0);
      sX[row][64 + ct1*16 + colb] = f2bf(acc1[r] + bias1);
    }
  }
  // x_a -> sX[:,0:64]  (8 threads/row, 8 cols each)
  {
    int r2 = tid >> 3;
    int n2 = n0 + r2; if (n2 >= NRES) n2 = NRES - 1;
    int c0 = (tid & 7) * 8;
    int zz = z[n2];
    float bbv[6], sdv[8];
    #pragma unroll
    for (int k = 0; k < 6; ++k) bbv[k] = bb[n2*6 + k];
    #pragma unroll
    for (int k = 0; k < 8; ++k) sdv[k] = side[n2*8 + k];
    #pragma unroll
    for (int c = 0; c < 8; c += 2) {
      float u0, u1;
      #pragma unroll
      for (int h = 0; h < 2; ++h) {
        int col = c0 + c + h;
        float a2 = W_emb[zz*64 + col] + b_emb[col];
        #pragma unroll
        for (int k = 0; k < 6; ++k) a2 += bbv[k] * W_emb[(26 + k)*64 + col];
        #pragma unroll
        for (int k = 0; k < 8; ++k) a2 += sdv[k] * W_emb[(32 + k)*64 + col];
        if (h) u1 = a2; else u0 = a2;
      }
      *(unsigned*)&sX[r2][c0 + c] = pkbf(u0, u1);
    }
  }
  __syncthreads();

  // xb global write + msg GEMM from sX
  #pragma unroll
  for (int it = 0; it < 2; ++it) {
    int idx = it * 512 + tid;
    int row = idx >> 4, c8 = idx & 15;
    int n = n0 + row;
    if (n < NRES) *(short8*)&xb[(size_t)n * 128 + c8*8] = *(const short8*)&sX[row][c8*8];
  }

  floatx4 accM[4];
  #pragma unroll
  for (int mt = 0; mt < 4; ++mt) accM[mt] = (floatx4){0.f,0.f,0.f,0.f};
  #pragma unroll
  for (int kt = 0; kt < 4; ++kt) {
    short8 b0 = *(const short8*)&Wmf[(size_t)((kt*8 + w)*64 + lane)*8];
    #pragma unroll
    for (int mt = 0; mt < 4; ++mt) {
      short8 a = *(const short8*)&sX[mt*16 + colb][kt*32 + quad*8];
      accM[mt] = __builtin_amdgcn_mfma_f32_16x16x32_bf16(a, b0, accM[mt], 0, 0, 0);
    }
  }
  __syncthreads();   // all sX reads done before overwrite

  // xm -> sX, then coalesced xmb write
  #pragma unroll
  for (int mt = 0; mt < 4; ++mt)
    #pragma unroll
    for (int r = 0; r < 4; ++r)
      sX[mt*16 + quad*4 + r][w*16 + colb] = f2bf(swish_fast(accM[mt][r]));
  __syncthreads();
  #pragma unroll
  for (int it = 0; it < 2; ++it) {
    int idx = it * 512 + tid;
    int row = idx >> 4, c8 = idx & 15;
    int n = n0 + row;
    if (n < NRES) *(short8*)&xmb[(size_t)n * 128 + c8*8] = *(const short8*)&sX[row][c8*8];
  }
}

// ---------------------------------------------------------------------------
// FULL-PATH edge kernel (R6-proven): 64 SORTED edges/block; all 256 threads
// do geometry (4 threads/edge, quarter-split); single GEMM; run-merged scatter.
__global__ __launch_bounds__(256, 4) void k_edge_s(
    const int2* __restrict__ sij,
    const float* __restrict__ pos,
    const float* __restrict__ posn, const float* __restrict__ posc,
    const short* __restrict__ xmb, const short* __restrict__ Wef,
    short* __restrict__ aggb)
{
  __shared__ int sJ[64];
  __shared__ int sI[64];
  __shared__ __align__(16) short sF[64][136];
  __shared__ __align__(16) short sXJ[64][136];

  const int tid = threadIdx.x;
  // bijective XCD swizzle: nwg=15625, 8 XCDs, q=1953, r=1
  const int orig = blockIdx.x;
  const int xcd = orig & 7, sub = orig >> 3;
  const int wg = (xcd == 0 ? 0 : 1954 + (xcd - 1) * 1953) + sub;
  const int e0 = wg * 64;

  if (tid < 64) {
    int2 ji = sij[e0 + tid];
    int jj = ji.x, ii = ji.y;
    sJ[tid] = (jj < 0) ? 0 : ((jj >= NRES) ? NRES - 1 : jj);
    sI[tid] = (ii < 0) ? 0 : ((ii >= NRES) ? NRES - 1 : ii);
  }
  __syncthreads();

  // all threads: geometry for edge tid&63, feature quarter tid>>6
  {
    const int e = tid & 63, q = tid >> 6;
    edge_features_q(e, sJ[e], sI[e], q, pos, posn, posc, sF);
  }
  // all threads: xmb gather for sXJ (4 short8 each)
  #pragma unroll
  for (int it = 0; it < 4; ++it) {
    int idx = it * 256 + tid;
    int row = idx >> 4;
    int c8 = idx & 15;
    *(short8*)&sXJ[row][c8*8] = *(const short8*)&xmb[(size_t)sJ[row] * 128 + c8*8];
  }
  __syncthreads();

  const int lane = tid & 63, w = tid >> 6;
  const int quad = lane >> 4, colb = lane & 15;
  const int nb = w * 2;

  short8 bE[4][2];
  #pragma unroll
  for (int kt = 0; kt < 4; ++kt)
    #pragma unroll
    for (int nt = 0; nt < 2; ++nt)
      bE[kt][nt] = *(const short8*)&Wef[(size_t)((kt*8 + nb + nt)*64 + lane)*8];

  floatx4 accE[4][2];
  #pragma unroll
  for (int mt = 0; mt < 4; ++mt) {
    accE[mt][0] = (floatx4){0.f, 0.f, 0.f, 0.f};
    accE[mt][1] = (floatx4){0.f, 0.f, 0.f, 0.f};
  }

  #pragma unroll
  for (int kt = 0; kt < 4; ++kt) {
    #pragma unroll
    for (int mt = 0; mt < 4; ++mt) {
      short8 af = *(const short8*)&sF[mt*16 + colb][kt*32 + quad*8];
      #pragma unroll
      for (int nt = 0; nt < 2; ++nt)
        accE[mt][nt] = __builtin_amdgcn_mfma_f32_16x16x32_bf16(af, bE[kt][nt], accE[mt][nt], 0, 0, 0);
    }
  }
  __syncthreads();   // all sF reads done; reuse sF as m-staging

  short (*sM)[136] = sF;
  #pragma unroll
  for (int mt = 0; mt < 4; ++mt)
    #pragma unroll
    for (int nt = 0; nt < 2; ++nt) {
      int ch = w*32 + nt*16 + colb;
      #pragma unroll
      for (int r = 0; r < 4; ++r) {
        int e = mt*16 + quad*4 + r;
        float mv = bf2f(sXJ[e][ch]) * swish_fast(accE[mt][nt][r]);
        sM[e][ch] = f2bf(mv);
      }
    }
  __syncthreads();

  // run-merged scatter: edges sorted by i -> one pk-bf16 atomic per run.
  {
    const int p = tid & 63;        // channel pair
    const int g = tid >> 6;        // 16-row group == wave id
    float ax = 0.f, ay = 0.f;
    int cur = sI[g * 16];
    #pragma unroll
    for (int rr = 0; rr < 16; ++rr) {
      int row = g * 16 + rr;
      int ii = sI[row];
      if (ii != cur) {
        bf16x2 v; v[0] = f2bf(ax); v[1] = f2bf(ay);
        atom_pk_bf16(&aggb[(size_t)cur * 128 + p*2], v);
        ax = 0.f; ay = 0.f; cur = ii;
      }
      bf16x2 mv = *(const bf16x2*)&sM[row][p*2];
      ax += bf2f(mv[0]); ay += bf2f(mv[1]);
    }
    bf16x2 v; v[0] = f2bf(ax); v[1] = f2bf(ay);
    atom_pk_bf16(&aggb[(size_t)cur * 128 + p*2], v);
  }
}

// ---------------------------------------------------------------------------
// FALLBACK edge kernel (round-0 baseline): unsorted, two GEMMs,
// per-edge pk-bf16 atomics.
__global__ __launch_bounds__(256, 4) void k_edge_b(
    const int* __restrict__ ei, const float* __restrict__ pos,
    const float* __restrict__ posn, const float* __restrict__ posc,
    const short* __restrict__ xb, const short* __restrict__ Wef,
    const short* __restrict__ Wmf, short* __restrict__ aggb)
{
  __shared__ int sJ[64];
  __shared__ int sI[64];
  __shared__ __align__(16) short sF[64][136];
  __shared__ __align__(16) short sXJ[64][136];

  const int tid = threadIdx.x;
  const int e0 = blockIdx.x * 64;

  if (tid < 64) { sJ[tid] = ei[e0 + tid]; sI[tid] = ei[NEDGE + e0 + tid]; }
  __syncthreads();

  if (tid < 64) {
    edge_features_full(tid, sJ[tid], sI[tid], pos, posn, posc, sF);
  } else {
    const int t2 = tid - 64;
    for (int it = 0; it < 6; ++it) {
      int idx = it * 192 + t2;
      if (idx < 1024) {
        int row = idx >> 4;
        int c8 = idx & 15;
        *(short8*)&sXJ[row][c8*8] = *(const short8*)&xb[(size_t)sJ[row] * 128 + c8*8];
      }
    }
  }
  __syncthreads();

  const int lane = tid & 63, w = tid >> 6;
  const int quad = lane >> 4, colb = lane & 15;
  const int nb = w * 2;

  short8 bE[4][2], bM[4][2];
  #pragma unroll
  for (int kt = 0; kt < 4; ++kt)
    #pragma unroll
    for (int nt = 0; nt < 2; ++nt) {
      bE[kt][nt] = *(const short8*)&Wef[(size_t)((kt*8 + nb + nt)*64 + lane)*8];
      bM[kt][nt] = *(const short8*)&Wmf[(size_t)((kt*8 + nb + nt)*64 + lane)*8];
    }

  floatx4 accE[4][2], accM[4][2];
  #pragma unroll
  for (int mt = 0; mt < 4; ++mt)
    #pragma unroll
    for (int nt = 0; nt < 2; ++nt) {
      accE[mt][nt] = (floatx4){0.f, 0.f, 0.f, 0.f};
      accM[mt][nt] = (floatx4){0.f, 0.f, 0.f, 0.f};
    }

  #pragma unroll
  for (int kt = 0; kt < 4; ++kt) {
    #pragma unroll
    for (int mt = 0; mt < 4; ++mt) {
      short8 af = *(const short8*)&sF [mt*16 + colb][kt*32 + quad*8];
      short8 ax = *(const short8*)&sXJ[mt*16 + colb][kt*32 + quad*8];
      #pragma unroll
      for (int nt = 0; nt < 2; ++nt) {
        accE[mt][nt] = __builtin_amdgcn_mfma_f32_16x16x32_bf16(af, bE[kt][nt], accE[mt][nt], 0, 0, 0);
        accM[mt][nt] = __builtin_amdgcn_mfma_f32_16x16x32_bf16(ax, bM[kt][nt], accM[mt][nt], 0, 0, 0);
      }
    }
  }
  __syncthreads();

  short (*sM)[136] = sXJ;
  #pragma unroll
  for (int mt = 0; mt < 4; ++mt)
    #pragma unroll
    for (int nt = 0; nt < 2; ++nt) {
      int ch = w*32 + nt*16 + colb;
      #pragma unroll
      for (int r = 0; r < 4; ++r) {
        int e = mt*16 + quad*4 + r;
        sM[e][ch] = f2bf(swish_fast(accM[mt][nt][r]) * swish_fast(accE[mt][nt][r]));
      }
    }
  __syncthreads();

  #pragma unroll
  for (int it = 0; it < 16; ++it) {
    int flat = it * 256 + tid;
    int row = flat >> 6, p = flat & 63;
    bf16x2 v = *(const bf16x2*)&sM[row][p*2];
    atom_pk_bf16(&aggb[(size_t)sI[row] * 128 + p*2], v);
  }
}

// ---------------------------------------------------------------------------
// fused update + both heads (R6-proven). 64 nodes/block, 256 threads.
__global__ __launch_bounds__(256) void k_upd(
    const short* __restrict__ xb, const short* __restrict__ aggb,
    const short* __restrict__ Wuf, const short* __restrict__ Wo0f,
    const short* __restrict__ Wn0f, const short* __restrict__ Wo1f,
    const float* __restrict__ bn0, const float* __restrict__ Wnf,
    const float* __restrict__ bnf, const float* __restrict__ bo0,
    const float* __restrict__ bo1, const float* __restrict__ Wof,
    const float* __restrict__ bof, float* __restrict__ out0,
    float* __restrict__ out1)
{
  __shared__ __align__(16) short sA[64][136];
  __shared__ __align__(16) short sX[64][136];
  __shared__ float sS[64][33];

  const int tid = threadIdx.x;
  const int lane = tid & 63, w = tid >> 6;
  const int quad = lane >> 4, colb = lane & 15;
  const int n0 = blockIdx.x * 64;

  #pragma unroll
  for (int it = 0; it < 4; ++it) {
    int idx = it * 256 + tid;
    int row = idx >> 4, c8 = idx & 15;
    int n = n0 + row;
    short8 va = (short8)(short)0, vx = (short8)(short)0;
    if (n < NRES) {
      va = *(const short8*)&aggb[(size_t)n * 128 + c8*8];
      vx = *(const short8*)&xb  [(size_t)n * 128 + c8*8];
    }
    *(short8*)&sA[row][c8*8] = va;
    *(short8*)&sX[row][c8*8] = vx;
  }
  __syncthreads();

  // hn = relu(x@Wn0+bn0); wave w handles mtile w
  {
    floatx4 accN[2];
    accN[0] = (floatx4){0.f,0.f,0.f,0.f}; accN[1] = (floatx4){0.f,0.f,0.f,0.f};
    #pragma unroll
    for (int kt = 0; kt < 4; ++kt) {
      short8 a = *(const short8*)&sX[w*16 + colb][kt*32 + quad*8];
      #pragma unroll
      for (int nt = 0; nt < 2; ++nt) {
        short8 bf = *(const short8*)&Wn0f[(size_t)((kt*2 + nt)*64 + lane)*8];
        accN[nt] = __builtin_amdgcn_mfma_f32_16x16x32_bf16(a, bf, accN[nt], 0, 0, 0);
      }
    }
    #pragma unroll
    for (int nt = 0; nt < 2; ++nt) {
      int col = nt*16 + colb;
      float bias = bn0[col];
      #pragma unroll
      for (int r = 0; r < 4; ++r)
        sS[w*16 + quad*4 + r][col] = fmaxf(accN[nt][r] + bias, 0.0f);
    }
  }
  __syncthreads();
  if (tid < 128) {
    int row = tid >> 1, oc = tid & 1;
    int n = n0 + row;
    if (n < NRES) {
      float a2 = bnf[oc];
      #pragma unroll
      for (int k = 0; k < 32; ++k) a2 += sS[row][k] * Wnf[k*2 + oc];
      out1[(size_t)n * 2 + oc] = a2;
    }
  }

  // GEMM1: t = agg@Wu
  floatx4 acc1[4][2];
  #pragma unroll
  for (int mt = 0; mt < 4; ++mt) {
    acc1[mt][0] = (floatx4){0.f,0.f,0.f,0.f};
    acc1[mt][1] = (floatx4){0.f,0.f,0.f,0.f};
  }
  #pragma unroll
  for (int kt = 0; kt < 4; ++kt) {
    short8 b0 = *(const short8*)&Wuf[(size_t)((kt*8 + w*2 + 0)*64 + lane)*8];
    short8 b1 = *(const short8*)&Wuf[(size_t)((kt*8 + w*2 + 1)*64 + lane)*8];
    #pragma unroll
    for (int mt = 0; mt < 4; ++mt) {
      short8 a = *(const short8*)&sA[mt*16 + colb][kt*32 + quad*8];
      acc1[mt][0] = __builtin_amdgcn_mfma_f32_16x16x32_bf16(a, b0, acc1[mt][0], 0, 0, 0);
      acc1[mt][1] = __builtin_amdgcn_mfma_f32_16x16x32_bf16(a, b1, acc1[mt][1], 0, 0, 0);
    }
  }
  __syncthreads();
  // xe = x + swish(t)
  #pragma unroll
  for (int mt = 0; mt < 4; ++mt)
    #pragma unroll
    for (int nt = 0; nt < 2; ++nt)
      #pragma unroll
      for (int r = 0; r < 4; ++r) {
        int row = mt*16 + quad*4 + r, col = w*32 + nt*16 + colb;
        float xv = bf2f(sX[row][col]);
        sA[row][col] = f2bf(xv + swish_fast(acc1[mt][nt][r]));
      }
  __syncthreads();

  // GEMM2: h = relu(xe@Wo0 + bo0)
  floatx4 acc2[4][2];
  #pragma unroll
  for (int mt = 0; mt < 4; ++mt) {
    acc2[mt][0] = (floatx4){0.f,0.f,0.f,0.f};
    acc2[mt][1] = (floatx4){0.f,0.f,0.f,0.f};
  }
  #pragma unroll
  for (int kt = 0; kt < 4; ++kt) {
    short8 b0 = *(const short8*)&Wo0f[(size_t)((kt*8 + w*2 + 0)*64 + lane)*8];
    short8 b1 = *(const short8*)&Wo0f[(size_t)((kt*8 + w*2 + 1)*64 + lane)*8];
    #pragma unroll
    for (int mt = 0; mt < 4; ++mt) {
      short8 a = *(const short8*)&sA[mt*16 + colb][kt*32 + quad*8];
      acc2[mt][0] = __builtin_amdgcn_mfma_f32_16x16x32_bf16(a, b0, acc2[mt][0], 0, 0, 0);
      acc2[mt][1] = __builtin_amdgcn_mfma_f32_16x16x32_bf16(a, b1, acc2[mt][1], 0, 0, 0);
    }
  }
  __syncthreads();
  #pragma unroll
  for (int mt = 0; mt < 4; ++mt)
    #pragma unroll
    for (int nt = 0; nt < 2; ++nt) {
      int col = w*32 + nt*16 + colb;
      float bias = bo0[col];
      #pragma unroll
      for (int r = 0; r < 4; ++r) {
        int row = mt*16 + quad*4 + r;
        sX[row][col] = f2bf(fmaxf(acc2[mt][nt][r] + bias, 0.0f));
      }
    }
  __syncthreads();

  // GEMM3: h2 = relu(h@Wo1 + bo1); wave w handles mtile w
  {
    floatx4 accH[2];
    accH[0] = (floatx4){0.f,0.f,0.f,0.f}; accH[1] = (floatx4){0.f,0.f,0.f,0.f};
    #pragma unroll
    for (int kt = 0; kt < 4; ++kt) {
      short8 a = *(const short8*)&sX[w*16 + colb][kt*32 + quad*8];
      #pragma unroll
      for (int nt = 0; nt < 2; ++nt) {
        short8 bf = *(const short8*)&Wo1f[(size_t)((kt*2 + nt)*64 + lane)*8];
        accH[nt] = __builtin_amdgcn_mfma_f32_16x16x32_bf16(a, bf, accH[nt], 0, 0, 0);
      }
    }
    __syncthreads();
    #pragma unroll
    for (int nt = 0; nt < 2; ++nt) {
      int col = nt*16 + colb;
      float bias = bo1[col];
      #pragma unroll
      for (int r = 0; r < 4; ++r)
        sS[w*16 + quad*4 + r][col] = fmaxf(accH[nt][r] + bias, 0.0f);
    }
  }
  __syncthreads();

  if (tid < 64) {
    int n = n0 + tid;
    if (n < NRES) {
      float a2 = bof[0];
      #pragma unroll
      for (int k = 0; k < 32; ++k) a2 += sS[tid][k] * Wof[k];
      out0[n] = 1.0f / (1.0f + expf(-a2));
    }
  }
}

// ---------------------------------------------------------------------------
extern "C" void kernel_launch(void* const* d_in, const int* in_sizes, int n_in,
                              void* d_out, int out_size, void* d_ws, size_t ws_size,
                              hipStream_t stream) {
  (void)in_sizes; (void)n_in; (void)out_size;
  const int*   z     = (const int*)  d_in[0];
  const float* pos   = (const float*)d_in[1];
  const float* posn  = (const float*)d_in[2];
  const float* posc  = (const float*)d_in[3];
  const float* bb    = (const float*)d_in[4];
  const float* side  = (const float*)d_in[5];
  const float* esm   = (const float*)d_in[6];
  const int*   ei    = (const int*)  d_in[8];
  const float* W_emb = (const float*)d_in[9];
  const float* b_emb = (const float*)d_in[10];
  const float* W_esm = (const float*)d_in[11];
  const float* b_esm = (const float*)d_in[12];
  const float* W_edge= (const float*)d_in[13];
  const float* W_msg = (const float*)d_in[14];
  const float* W_upd = (const float*)d_in[15];
  const float* W_o0  = (const float*)d_in[16];
  const float* b_o0  = (const float*)d_in[17];
  const float* W_o1  = (const float*)d_in[18];
  const float* b_o1  = (const float*)d_in[19];
  const float* W_of  = (const float*)d_in[20];
  const float* b_of  = (const float*)d_in[21];
  const float* W_n0  = (const float*)d_in[22];
  const float* b_n0  = (const float*)d_in[23];
  const float* W_nf  = (const float*)d_in[24];
  const float* b_nf  = (const float*)d_in[25];

  float* out0 = (float*)d_out;                         // [N]
  float* out1 = out0 + NRES;                           // [N,2]
  char* ws = (char*)d_ws;

  const bool full = (ws_size >= (size_t)46912096);

  if (full) {
    // ---- full layout (~46.9 MB) ----
    short* xb   = (short*)ws;                          // 12,800,000 B
    short* aggb = (short*)(ws + 12800000);             // 12,800,000 B
    short* xmb  = (short*)(ws + 25600000);             // 12,800,000 B
    short* Wef  = (short*)(ws + 38400000);             // 32,768 B
    short* Wmf  = (short*)(ws + 38432768);             // 32,768 B
    short* Wsf  = (short*)(ws + 38465536);             // 163,840 B
    short* Wuf  = (short*)(ws + 38629376);             // 32,768 B
    short* Wo0f = (short*)(ws + 38662144);             // 32,768 B
    short* Wn0f = (short*)(ws + 38694912);             // 8,192 B
    short* Wo1f = (short*)(ws + 38703104);             // 8,192 B
    int*   bins = (int*)  (ws + 38711296);             // 200,000 B
    int*   bsum = (int*)  (ws + 38911296);             // 800 B
    int2*  sij  = (int2*) (ws + 38912096);             // 8,000,000 B

    hipMemsetAsync(aggb, 0, (size_t)NRES * 128 * sizeof(short), stream);
    hipMemsetAsync(bins, 0, (size_t)NRES * sizeof(int), stream);

    k_wprep  <<<608, 256, 0, stream>>>(W_edge, W_msg, W_esm, W_upd, W_o0,
                                       W_n0, W_o1, Wef, Wmf, Wsf, Wuf,
                                       Wo0f, Wn0f, Wo1f);
    k_hist   <<<3907, 256, 0, stream>>>(ei, bins);
    k_scan1  <<<NSEG, 256, 0, stream>>>(bins, bsum);
    k_scan2  <<<1,    256, 0, stream>>>(bsum);
    k_scatter<<<3907, 256, 0, stream>>>(ei, bins, bsum, sij);
    k_node   <<<782,  512, 0, stream>>>(esm, Wsf, b_esm, z, bb, side, W_emb, b_emb,
                                        Wmf, xb, xmb);
    k_edge_s <<<15625, 256, 0, stream>>>(sij, pos, posn, posc, xmb, Wef, aggb);
    k_upd    <<<782,   256, 0, stream>>>(xb, aggb, Wuf, Wo0f, Wn0f, Wo1f,
                                         b_n0, W_nf, b_nf, b_o0, b_o1, W_of, b_of,
                                         out0, out1);
  } else {
    // ---- fallback: round-0 proven layout (25.9 MB) ----
    short* xb   = (short*)ws;                          // 12,800,000 B
    short* aggb = (short*)(ws + 12800000);             // 12,800,000 B
    short* Wef  = (short*)(ws + 25600000);             // 32,768 B
    short* Wmf  = (short*)(ws + 25632768);             // 32,768 B
    short* Wsf  = (short*)(ws + 25665536);             // 163,840 B
    short* Wuf  = (short*)(ws + 25829376);             // 32,768 B
    short* Wo0f = (short*)(ws + 25862144);             // 32,768 B
    short* Wn0f = (short*)(ws + 25894912);             // 8,192 B
    short* Wo1f = (short*)(ws + 25903104);             // 8,192 B

    hipMemsetAsync(aggb, 0, (size_t)NRES * 128 * sizeof(short), stream);

    k_wprep <<<608, 256, 0, stream>>>(W_edge, W_msg, W_esm, W_upd, W_o0, W_n0, W_o1,
                                      Wef, Wmf, Wsf, Wuf, Wo0f, Wn0f, Wo1f);
    k_xa    <<<12500, 256, 0, stream>>>(z, bb, side, W_emb, b_emb, xb);
    k_esm   <<<782,   256, 0, stream>>>(esm, Wsf, b_esm, xb);
    k_edge_b<<<15625, 256, 0, stream>>>(ei, pos, posn, posc, xb, Wef, Wmf, aggb);
    k_upd   <<<782,   256, 0, stream>>>(xb, aggb, Wuf, Wo0f, Wn0f, Wo1f,
                                        b_n0, W_nf, b_nf, b_o0, b_o1, W_of, b_of,
                                        out0, out1);
  }
}